// Round 1
// baseline (1464.414 us; speedup 1.0000x reference)
//
#include <hip/hip_runtime.h>
#include <cstddef>

#define B_ 32
#define T_ 128
#define N_ 200
#define FI_ 32
#define FO_ 64
#define K_ 3
#define TT_ 16      // t-values per thread
#define TILE_T_ 64  // t-values per block (4 waves x TT_)

// Each block: one (b, n, t-tile of 64). 256 threads = 4 waves.
// lane f = tid&63 owns output feature f; wave wv = tid>>6 owns t-subrange.
__global__ __launch_bounds__(256, 2) void multiconv_kernel(
    const float* __restrict__ x, const float* __restrict__ w,
    const float* __restrict__ bias, float* __restrict__ out)
{
    __shared__ float xs[(TILE_T_ + 2) * FI_];  // 66 rows x 32 ch = 8448 B

    const int bid = blockIdx.x;
    const int n = bid % N_;
    const int tmp = bid / N_;
    const int tile = tmp & 1;
    const int b = tmp >> 1;
    const int t_base = tile * TILE_T_;
    const int tid = threadIdx.x;

    // ---- stage x rows [t_base-1 .. t_base+TILE_T_] into LDS (zero-padded) ----
    const int NSLOT = (TILE_T_ + 2) * (FI_ / 4);  // 528 float4 slots
    for (int s = tid; s < NSLOT; s += 256) {
        const int row = s >> 3;   // /(FI_/4)
        const int i4 = s & 7;
        const int gt = t_base + row - 1;
        float4 v = make_float4(0.f, 0.f, 0.f, 0.f);
        if (gt >= 0 && gt < T_) {
            v = *reinterpret_cast<const float4*>(
                &x[(((size_t)b * T_ + gt) * N_ + n) * FI_ + i4 * 4]);
        }
        *reinterpret_cast<float4*>(&xs[row * FI_ + i4 * 4]) = v;
    }

    const int f  = tid & 63;
    const int wv = tid >> 6;

    // ---- per-lane weights into registers (96 fp32, compile-time indexed) ----
    float wreg[FI_ * K_];
    const float* wp = &w[((size_t)n * FO_ + f) * (FI_ * K_)];
    #pragma unroll
    for (int j = 0; j < (FI_ * K_) / 4; ++j) {
        const float4 v = *reinterpret_cast<const float4*>(&wp[j * 4]);
        wreg[j * 4 + 0] = v.x; wreg[j * 4 + 1] = v.y;
        wreg[j * 4 + 2] = v.z; wreg[j * 4 + 3] = v.w;
    }
    const float bv = bias[n * FO_ + f];

    __syncthreads();

    float acc[TT_];
    #pragma unroll
    for (int t = 0; t < TT_; ++t) acc[t] = 0.f;

    const int r0 = wv * TT_;  // this wave's base row in LDS

    // LDS row r (wave-local) contributes to acc[r-k] with weight [i*3+k].
    // All xs reads are wave-uniform addresses -> broadcast, conflict-free b128.
#define DO_ELEM(I, XE)                                                    \
    {                                                                     \
        if ((r - 0) >= 0 && (r - 0) < TT_) acc[r - 0] += wreg[(I)*3 + 0] * (XE); \
        if ((r - 1) >= 0 && (r - 1) < TT_) acc[r - 1] += wreg[(I)*3 + 1] * (XE); \
        if ((r - 2) >= 0 && (r - 2) < TT_) acc[r - 2] += wreg[(I)*3 + 2] * (XE); \
    }

    #pragma unroll
    for (int r = 0; r < TT_ + 2; ++r) {
        #pragma unroll
        for (int i4 = 0; i4 < FI_ / 4; ++i4) {
            const float4 xv = *reinterpret_cast<const float4*>(
                &xs[(r0 + r) * FI_ + i4 * 4]);
            const int ib = i4 * 4;
            DO_ELEM(ib + 0, xv.x);
            DO_ELEM(ib + 1, xv.y);
            DO_ELEM(ib + 2, xv.z);
            DO_ELEM(ib + 3, xv.w);
        }
    }
#undef DO_ELEM

    // ---- epilogue: bias + coalesced store (64 lanes x consecutive f) ----
    const int gt0 = t_base + r0;
    #pragma unroll
    for (int tt = 0; tt < TT_; ++tt) {
        out[(((size_t)b * T_ + (gt0 + tt)) * N_ + n) * FO_ + f] = acc[tt] + bv;
    }
}

extern "C" void kernel_launch(void* const* d_in, const int* in_sizes, int n_in,
                              void* d_out, int out_size, void* d_ws, size_t ws_size,
                              hipStream_t stream) {
    const float* x    = (const float*)d_in[0];
    const float* w    = (const float*)d_in[1];
    const float* bias = (const float*)d_in[2];
    float* out = (float*)d_out;

    const int grid = B_ * 2 * N_;  // 12800 blocks: (b, tile, n), n fastest
    multiconv_kernel<<<grid, 256, 0, stream>>>(x, w, bias, out);
}

// Round 2
// 212.011 us; speedup vs baseline: 6.9073x; 6.9073x over previous
//
#include <hip/hip_runtime.h>
#include <cstddef>

#define B_ 32
#define T_ 128
#define N_ 200
#define FI_ 32
#define FO_ 64
#define K_ 3
#define TT_ 16      // t-values per thread
#define TILE_T_ 64  // t-values per block (4 waves x TT_)
#define CH_ 8       // input channels per register chunk
#define NCH_ (FI_ / CH_)

// Each block: one (b, n, t-tile of 64). 256 threads = 4 waves.
// lane f = tid&63 owns output feature f; wave wv = tid>>6 owns t-subrange.
// Weights are consumed in chunks of 8 input channels (24 floats live) to keep
// VGPR pressure ~70 and avoid the scratch-spill thrash seen in R1
// (4.06 GB WRITE_SIZE vs 0.21 GB output).
__global__ __launch_bounds__(256, 4) void multiconv_kernel(
    const float* __restrict__ x, const float* __restrict__ w,
    const float* __restrict__ bias, float* __restrict__ out)
{
    __shared__ float xs[(TILE_T_ + 2) * FI_];  // 66 rows x 32 ch = 8448 B

    const int bid = blockIdx.x;
    const int n = bid % N_;
    const int tmp = bid / N_;
    const int tile = tmp & 1;
    const int b = tmp >> 1;
    const int t_base = tile * TILE_T_;
    const int tid = threadIdx.x;

    // ---- stage x rows [t_base-1 .. t_base+TILE_T_] into LDS (zero-padded) ----
    const int NSLOT = (TILE_T_ + 2) * (FI_ / 4);  // 528 float4 slots
    for (int s = tid; s < NSLOT; s += 256) {
        const int row = s >> 3;   // /(FI_/4)
        const int i4 = s & 7;
        const int gt = t_base + row - 1;
        float4 v = make_float4(0.f, 0.f, 0.f, 0.f);
        if (gt >= 0 && gt < T_) {
            v = *reinterpret_cast<const float4*>(
                &x[(((size_t)b * T_ + gt) * N_ + n) * FI_ + i4 * 4]);
        }
        *reinterpret_cast<float4*>(&xs[row * FI_ + i4 * 4]) = v;
    }

    const int f  = tid & 63;
    const int wv = tid >> 6;
    const float* wp = &w[((size_t)n * FO_ + f) * (FI_ * K_)];
    const float bv = bias[n * FO_ + f];

    __syncthreads();

    float acc[TT_];
    #pragma unroll
    for (int t = 0; t < TT_; ++t) acc[t] = 0.f;

    const int r0 = wv * TT_;  // this wave's base row in LDS

    // Chunked over input channels: only CH_*K_=24 weight regs live at a time.
    #pragma unroll 1
    for (int c = 0; c < NCH_; ++c) {
        float wreg[CH_ * K_];
        #pragma unroll
        for (int j = 0; j < (CH_ * K_) / 4; ++j) {   // 6x float4, 16B-aligned
            const float4 v = *reinterpret_cast<const float4*>(
                &wp[c * CH_ * K_ + j * 4]);
            wreg[j * 4 + 0] = v.x; wreg[j * 4 + 1] = v.y;
            wreg[j * 4 + 2] = v.z; wreg[j * 4 + 3] = v.w;
        }

        #pragma unroll
        for (int r = 0; r < TT_ + 2; ++r) {
            // wave-uniform LDS reads -> broadcast, conflict-free
            const float4 xa = *reinterpret_cast<const float4*>(
                &xs[(r0 + r) * FI_ + c * CH_]);
            const float4 xb = *reinterpret_cast<const float4*>(
                &xs[(r0 + r) * FI_ + c * CH_ + 4]);
            const float xe[CH_] = {xa.x, xa.y, xa.z, xa.w,
                                   xb.x, xb.y, xb.z, xb.w};
            #pragma unroll
            for (int i = 0; i < CH_; ++i) {
                #pragma unroll
                for (int k = 0; k < K_; ++k) {
                    const int o = r - k;          // compile-time
                    if (o >= 0 && o < TT_)
                        acc[o] += wreg[i * K_ + k] * xe[i];
                }
            }
        }
    }

    // ---- epilogue: bias + coalesced store (64 lanes x consecutive f) ----
    const int gt0 = t_base + r0;
    #pragma unroll
    for (int tt = 0; tt < TT_; ++tt) {
        out[(((size_t)b * T_ + (gt0 + tt)) * N_ + n) * FO_ + f] = acc[tt] + bv;
    }
}

extern "C" void kernel_launch(void* const* d_in, const int* in_sizes, int n_in,
                              void* d_out, int out_size, void* d_ws, size_t ws_size,
                              hipStream_t stream) {
    const float* x    = (const float*)d_in[0];
    const float* w    = (const float*)d_in[1];
    const float* bias = (const float*)d_in[2];
    float* out = (float*)d_out;

    const int grid = B_ * 2 * N_;  // 12800 blocks: (b, tile, n), n fastest
    multiconv_kernel<<<grid, 256, 0, stream>>>(x, w, bias, out);
}

// Round 3
// 78.594 us; speedup vs baseline: 18.6327x; 2.6976x over previous
//
#include <hip/hip_runtime.h>
#include <hip/hip_bf16.h>
#include <cstddef>

#define B_ 32
#define T_ 128
#define N_ 200
#define FI_ 32
#define FO_ 64
#define K_ 3

typedef __attribute__((ext_vector_type(8))) short short8;            // 8 bf16 (4 VGPR)
typedef __attribute__((ext_vector_type(8))) unsigned short ushort8;
typedef __attribute__((ext_vector_type(4))) float f32x4;

// LDS layout (ushort units). Row stride 40 ushorts = 80 B: banks advance by
// 20 mod 32 per row -> 16 consecutive rows give 2-way aliasing max (free, m136).
#define AROW_ 40
#define A_ROWS_ (T_ + 2)            // t = -1 .. 128, zero-padded edges
#define B_OFF_ (A_ROWS_ * AROW_)    // 5200
#define BROW_ 40
#define BK_SZ_ (FO_ * BROW_)        // 2560 ushorts per tap k

__device__ __forceinline__ unsigned short f2bf(float f) {
    union { __hip_bfloat16 h; unsigned short u; } cv;
    cv.h = __float2bfloat16(f);
    return cv.u;
}

// One block per (b, n): full T=128 output rows x all 64 f via MFMA.
// 4 waves, each owns 32 t-rows; 3 taps x 2 m-frags x 4 n-frags = 24 mfma/wave.
__global__ __launch_bounds__(256, 4) void multiconv_mfma(
    const float* __restrict__ x, const float* __restrict__ w,
    const float* __restrict__ bias, float* __restrict__ out)
{
    __shared__ __align__(16) unsigned short lds[B_OFF_ + K_ * BK_SZ_];  // 25760 B

    const int bid = blockIdx.x;
    const int b = bid & 31;    // batch
    const int n = bid >> 5;    // group; consecutive blocks share n -> w hits L2
    const int tid = threadIdx.x;
    const int lane = tid & 63;
    const int wv = tid >> 6;

    // ---- stage x[b, t, n, 0:32] for t = -1..128 as bf16 (rows of 32ch) ----
    const float* xb = x + ((size_t)b * T_ * N_ + n) * FI_;
    for (int s = tid; s < A_ROWS_ * 4; s += 256) {
        const int rr = s >> 2, q = s & 3;   // rr: LDS row, q: 8-channel slot
        const int t = rr - 1;
        ushort8 u = (ushort8)0;
        if (t >= 0 && t < T_) {
            const float4 v0 = *reinterpret_cast<const float4*>(
                &xb[(size_t)t * N_ * FI_ + q * 8]);
            const float4 v1 = *reinterpret_cast<const float4*>(
                &xb[(size_t)t * N_ * FI_ + q * 8 + 4]);
            u[0] = f2bf(v0.x); u[1] = f2bf(v0.y); u[2] = f2bf(v0.z); u[3] = f2bf(v0.w);
            u[4] = f2bf(v1.x); u[5] = f2bf(v1.y); u[6] = f2bf(v1.z); u[7] = f2bf(v1.w);
        }
        *reinterpret_cast<ushort8*>(&lds[rr * AROW_ + q * 8]) = u;
    }

    // ---- stage w[n,f,i,k] -> B_lds[k][f][i] bf16 (i contiguous per lane) ----
    {
        const int f = tid >> 2;
        const int i0 = (tid & 3) * 8;
        const float* wp = w + ((size_t)n * FO_ + f) * (FI_ * K_) + (size_t)i0 * K_;
        float v[24];
        #pragma unroll
        for (int j = 0; j < 6; ++j) {
            const float4 t4 = *reinterpret_cast<const float4*>(&wp[j * 4]);
            v[j*4+0] = t4.x; v[j*4+1] = t4.y; v[j*4+2] = t4.z; v[j*4+3] = t4.w;
        }
        #pragma unroll
        for (int k = 0; k < K_; ++k) {
            ushort8 u;
            #pragma unroll
            for (int j = 0; j < 8; ++j) u[j] = f2bf(v[j * K_ + k]);
            *reinterpret_cast<ushort8*>(&lds[B_OFF_ + k * BK_SZ_ + f * BROW_ + i0]) = u;
        }
    }

    __syncthreads();

    f32x4 acc[2][4];
    #pragma unroll
    for (int m = 0; m < 2; ++m)
        #pragma unroll
        for (int j = 0; j < 4; ++j)
            acc[m][j] = (f32x4){0.f, 0.f, 0.f, 0.f};

    const int row16 = lane & 15;
    const int grp = lane >> 4;

    // out[t] += x[t + k - 1] @ W_k ; LDS A-row = t + k (t offset by +1 for pad)
    #pragma unroll
    for (int k = 0; k < K_; ++k) {
        const short8 a0 = *reinterpret_cast<const short8*>(
            &lds[(wv * 32 + 0  + row16 + k) * AROW_ + grp * 8]);
        const short8 a1 = *reinterpret_cast<const short8*>(
            &lds[(wv * 32 + 16 + row16 + k) * AROW_ + grp * 8]);
        #pragma unroll
        for (int j = 0; j < 4; ++j) {
            const short8 bf = *reinterpret_cast<const short8*>(
                &lds[B_OFF_ + k * BK_SZ_ + (j * 16 + row16) * BROW_ + grp * 8]);
            acc[0][j] = __builtin_amdgcn_mfma_f32_16x16x32_bf16(a0, bf, acc[0][j], 0, 0, 0);
            acc[1][j] = __builtin_amdgcn_mfma_f32_16x16x32_bf16(a1, bf, acc[1][j], 0, 0, 0);
        }
    }

    // ---- epilogue: C/D layout col=lane&15, row=(lane>>4)*4+reg (m89) ----
    #pragma unroll
    for (int j = 0; j < 4; ++j) {
        const float bv = bias[n * FO_ + j * 16 + row16];
        #pragma unroll
        for (int m = 0; m < 2; ++m) {
            #pragma unroll
            for (int r = 0; r < 4; ++r) {
                const int t = wv * 32 + m * 16 + grp * 4 + r;
                out[(((size_t)b * T_ + t) * N_ + n) * FO_ + j * 16 + row16] =
                    acc[m][j][r] + bv;
            }
        }
    }
}

extern "C" void kernel_launch(void* const* d_in, const int* in_sizes, int n_in,
                              void* d_out, int out_size, void* d_ws, size_t ws_size,
                              hipStream_t stream) {
    const float* x    = (const float*)d_in[0];
    const float* w    = (const float*)d_in[1];
    const float* bias = (const float*)d_in[2];
    float* out = (float*)d_out;

    const int grid = B_ * N_;  // 6400 blocks: (n, b), b fastest
    multiconv_mfma<<<grid, 256, 0, stream>>>(x, w, bias, out);
}